// Round 11
// baseline (400.604 us; speedup 1.0000x reference)
//
#include <hip/hip_runtime.h>
#include <hip/hip_bf16.h>
#include <stdint.h>

// DenseGraphAttentionHead N=8192, IN=512, OUT=256, ~50% dense int32 mask.
//
// Pipeline:
//   k_mask      : int32 mask (268 MB, irreducible HBM stream) -> bitmask
//                 bm[row][wj] (8.4 MB) via __ballot. HBM-bound (~43 us).
//   k_convert_w : W f32 -> bf16 chunked (16B chunk (kb,row) at kb*2048+row*8).
//   k_wh        : Wh = nodes@W^T + b (mfma) -> WhL chunked bf16 + s1 f32 +
//                 FUSED exp-factorization tables (was k_prep):
//                 P = mask * (s1+s2>0 ? e^{s1}e^{s2} : e^{.2s1}e^{.2s2})
//                 sAC=[e^{s1}|e^{.2s1}] f32, sPK[j]={f32 e^{s2},
//                 u32(e^{.2s2}bf16 hi | s2 bf16 lo)}.
//   k_attn      : masked-softmax @ Wh on the bitmask. BK=64 (2x R9 — halves
//                 the per-step fixed cost: barrier + vmcnt drain paid 16x not
//                 32x). Grid 64rt x 8jc = 512 blocks; 512 thr = 8 waves =
//                 4 rowgroups(32) x 2 colhalves(128); acc 64 AGPR. LDS 72KB:
//                 2x32KB WhL dbuf (global_load_lds) + 8KB PK. 2 blocks/CU,
//                 16 waves/CU. Per step: stage slice u+1, 2 halfsteps x
//                 {PK from LDS, exp-free build, 16 MFMA w/ setprio}.
//   k_comb      : out = sum_jc(pnum) / sum_jc(pden), 8 partials.
//
// MFMA conventions (verified R1-R10 on this problem):
//   A frag: lane&15 = m, k = (lane>>4)*8 + i ; B same per-lane k order
//   D: col = lane&15, row = (lane>>4)*4 + reg

#define NN 8192
#define IND 512
#define OUTD 256

typedef __attribute__((ext_vector_type(8))) short short8;
typedef __attribute__((ext_vector_type(4))) short short4v;
typedef __attribute__((ext_vector_type(4))) float f32x4;
typedef __attribute__((ext_vector_type(4))) unsigned int u32x4;

#define AS_GLOBAL __attribute__((address_space(1)))
#define AS_LDS __attribute__((address_space(3)))

static __device__ __forceinline__ short f2bf(float f) {
  return __builtin_bit_cast(short, __float2bfloat16(f));
}

extern "C" __global__ __launch_bounds__(256) void k_convert_w(
    const float* __restrict__ W, short* __restrict__ W2) {
  const int t = blockIdx.x * 256 + threadIdx.x;  // 16384 threads
  const int row = t >> 6, kb = t & 63;
  const float* src = W + row * IND + kb * 8;
  f32x4 x0 = *(const f32x4*)src;
  f32x4 x1 = *(const f32x4*)(src + 4);
  short8 o;
  o[0] = f2bf(x0[0]); o[1] = f2bf(x0[1]); o[2] = f2bf(x0[2]); o[3] = f2bf(x0[3]);
  o[4] = f2bf(x1[0]); o[5] = f2bf(x1[1]); o[6] = f2bf(x1[2]); o[7] = f2bf(x1[3]);
  *(short8*)(W2 + (size_t)kb * 2048 + row * 8) = o;
}

extern "C" __global__ __launch_bounds__(128) void k_wh(
    const float* __restrict__ nodes, const short* __restrict__ W2,
    const float* __restrict__ Wb, const float* __restrict__ a1w,
    const float* __restrict__ a1b, const float* __restrict__ a2w,
    const float* __restrict__ a2b, short* __restrict__ WhL,
    float* __restrict__ s1, float* __restrict__ sAC,
    uint32_t* __restrict__ sPK) {
  const int tid = threadIdx.x;
  const int wv = tid >> 6, lane = tid & 63, g = lane >> 4, m = lane & 15;
  const int rowbase = blockIdx.x * 32 + wv * 16;

  f32x4 acc[16];
#pragma unroll
  for (int nf = 0; nf < 16; ++nf) acc[nf] = (f32x4){0.f, 0.f, 0.f, 0.f};

  const float* arow = nodes + (size_t)(rowbase + m) * IND;
  const short* bb = W2 + (size_t)g * 2048 + m * 8;
#pragma unroll 4
  for (int k0 = 0; k0 < IND; k0 += 32) {
    const float* ap = arow + k0 + g * 8;
    f32x4 x0 = *(const f32x4*)ap;
    f32x4 x1 = *(const f32x4*)(ap + 4);
    short8 af;
    af[0] = f2bf(x0[0]); af[1] = f2bf(x0[1]); af[2] = f2bf(x0[2]); af[3] = f2bf(x0[3]);
    af[4] = f2bf(x1[0]); af[5] = f2bf(x1[1]); af[6] = f2bf(x1[2]); af[7] = f2bf(x1[3]);
    const short* bk = bb + (size_t)(k0 >> 3) * 2048;
#pragma unroll
    for (int nf = 0; nf < 16; ++nf) {
      short8 bf = *(const short8*)(bk + nf * 128);
      acc[nf] = __builtin_amdgcn_mfma_f32_16x16x32_bf16(af, bf, acc[nf], 0, 0, 0);
    }
  }

  float p1[4] = {0.f, 0.f, 0.f, 0.f}, p2[4] = {0.f, 0.f, 0.f, 0.f};
#pragma unroll
  for (int nf = 0; nf < 16; ++nf) {
    const int n = nf * 16 + m;
    const float b = Wb[n], c1 = a1w[n], c2 = a2w[n];
#pragma unroll
    for (int r = 0; r < 4; ++r) {
      float v = acc[nf][r] + b;
      acc[nf][r] = v;
      p1[r] += c1 * v;
      p2[r] += c2 * v;
    }
  }
#pragma unroll
  for (int off = 1; off < 16; off <<= 1) {
#pragma unroll
    for (int r = 0; r < 4; ++r) {
      p1[r] += __shfl_xor(p1[r], off);
      p2[r] += __shfl_xor(p2[r], off);
    }
  }
  if (m == 0) {
    const float b1 = a1b[0], b2 = a2b[0];
#pragma unroll
    for (int r = 0; r < 4; ++r) {
      const int row = rowbase + g * 4 + r;
      const float v1 = p1[r] + b1, v2 = p2[r] + b2;
      s1[row] = v1;
      sAC[row] = __expf(v1);
      sAC[NN + row] = __expf(0.2f * v1);
      const float B = __expf(v2), D = __expf(0.2f * v2);
      sPK[2 * row] = __builtin_bit_cast(uint32_t, B);
      sPK[2 * row + 1] =
          ((uint32_t)(uint16_t)f2bf(D) << 16) | (uint16_t)f2bf(v2);
    }
  }

  const size_t cbase = ((size_t)(rowbase >> 3) + (g >> 1)) * 2048 + (g & 1) * 4;
#pragma unroll
  for (int nf = 0; nf < 16; ++nf) {
    short4v o;
#pragma unroll
    for (int r = 0; r < 4; ++r) o[r] = f2bf(acc[nf][r]);
    *(short4v*)(WhL + cbase + (size_t)(nf * 16 + m) * 8) = o;
  }
}

// int32 mask -> bitmask. bm[row*256 + wj] bit b = mask[row][wj*32+b] != 0.
extern "C" __global__ __launch_bounds__(256) void k_mask(
    const int* __restrict__ mask, uint32_t* __restrict__ bm) {
  const int tid = threadIdx.x;
  const int wv = tid >> 6, lane = tid & 63;
  const int gw = blockIdx.x * 4 + wv;           // 4096 waves
  const size_t base = (size_t)gw * 16384;       // 64 iters x 256 ints
#pragma unroll 4
  for (int it = 0; it < 64; ++it) {
    const size_t ib = base + (size_t)it * 256;
    unsigned long long b0 = __ballot(mask[ib + lane] != 0);
    unsigned long long b1 = __ballot(mask[ib + 64 + lane] != 0);
    unsigned long long b2 = __ballot(mask[ib + 128 + lane] != 0);
    unsigned long long b3 = __ballot(mask[ib + 192 + lane] != 0);
    if (lane < 8) {
      unsigned long long s01 = (lane & 2) ? b1 : b0;
      unsigned long long s23 = (lane & 2) ? b3 : b2;
      unsigned long long sel = (lane & 4) ? s23 : s01;
      bm[ib / 32 + lane] = (uint32_t)(sel >> ((lane & 1) * 32));
    }
  }
}

extern "C" __global__ __launch_bounds__(512, 4) void k_attn(
    const uint32_t* __restrict__ bm, const short* __restrict__ WhL,
    const float* __restrict__ s1, const float* __restrict__ sAC,
    const uint32_t* __restrict__ sPK,
    float* __restrict__ pnum, float* __restrict__ pden) {
  // LDS: [0,65536) 2x32KB WhL slice dbuf; [65536,73728) PK
  __shared__ char smem[73728];
  uint32_t* PKs = (uint32_t*)(smem + 65536);

  const int tid = threadIdx.x;
  const int w = tid >> 6, lane = tid & 63, g = lane >> 4, m = lane & 15;
  const int rt = blockIdx.x >> 3, jc = blockIdx.x & 7;
  const int rg = w & 3, ns = w >> 2;
  const int rb = rt * 128 + rg * 32;

  const float T0 = -s1[rb + m],        T1 = -s1[rb + 16 + m];
  const float A0 = sAC[rb + m],        A1 = sAC[rb + 16 + m];
  const float C0 = sAC[NN + rb + m],   C1 = sAC[NN + rb + 16 + m];

  f32x4 acc0[8], acc1[8];
#pragma unroll
  for (int nf = 0; nf < 8; ++nf) {
    acc0[nf] = (f32x4){0.f, 0.f, 0.f, 0.f};
    acc1[nf] = (f32x4){0.f, 0.f, 0.f, 0.f};
  }
  float den0 = 0.f, den1 = 0.f;

  // bm rows; step u consumes words 2u, 2u+1 (one aligned 8B load each row)
  const uint32_t* bw0 = bm + (size_t)(rb + m) * 256 + jc * 32;
  const uint32_t* bw1 = bw0 + (size_t)16 * 256;
  const short* gS = WhL + (size_t)jc * 262144;  // jc slice, 512 KiB

  // ---- prologue: PK (8 KB) + slice 0 (32 KB) ----
  __builtin_amdgcn_global_load_lds(
      (const AS_GLOBAL void*)((const char*)sPK + (size_t)jc * 8192 +
                              w * 1024 + lane * 16),
      (AS_LDS void*)(smem + 65536 + w * 1024), 16, 0, 0);
#pragma unroll
  for (int c = 0; c < 4; ++c) {
    __builtin_amdgcn_global_load_lds(
        (const AS_GLOBAL void*)(gS + w * 2048 + c * 512 + lane * 8),
        (AS_LDS void*)(smem + w * 4096 + c * 1024), 16, 0, 0);
  }
  uint64_t cw0 = *(const uint64_t*)(bw0);
  uint64_t cw1 = *(const uint64_t*)(bw1);
  __syncthreads();

  auto build = [&](float T, float A, float C, uint32_t mbits,
                   const u32x4& q0, const u32x4& q1,
                   const u32x4& q2, const u32x4& q3, float& den) -> short8 {
    const uint32_t Bv[8] = {q0[0], q0[2], q1[0], q1[2],
                            q2[0], q2[2], q3[0], q3[2]};
    const uint32_t Dv[8] = {q0[1], q0[3], q1[1], q1[3],
                            q2[1], q2[3], q3[1], q3[3]};
    short8 af;
#pragma unroll
    for (int i = 0; i < 8; ++i) {
      const float s2v = __builtin_bit_cast(float, Dv[i] << 16);
      const bool pos = s2v > T;
      const float wv = __builtin_bit_cast(float, pos ? Bv[i] : (Dv[i] & 0xFFFF0000u));
      const float a = pos ? A : C;
      const float val = wv * a;
      const float pv = ((mbits >> i) & 1u) ? val : 0.f;
      den += pv;
      af[i] = f2bf(pv);
    }
    return af;
  };

  // ---- main loop: 16 steps of 64 j ----
  for (int u = 0; u < 16; ++u) {
    // 1. stage slice u+1 into the other buffer (safe: buf (u+1)&1 was last
    //    read at step u-1; all waves are past that barrier)
    if (u < 15) {
      const short* gn = gS + (u + 1) * 16384 + w * 2048 + lane * 8;
      char* ld = smem + ((u + 1) & 1) * 32768 + w * 4096;
#pragma unroll
      for (int c = 0; c < 4; ++c) {
        __builtin_amdgcn_global_load_lds(
            (const AS_GLOBAL void*)(gn + c * 512),
            (AS_LDS void*)(ld + c * 1024), 16, 0, 0);
      }
    }
    // 2. prefetch next step's bm words (8B per row)
    const int un = (u < 15) ? u + 1 : 15;
    const uint64_t nw0 = *(const uint64_t*)(bw0 + 2 * un);
    const uint64_t nw1 = *(const uint64_t*)(bw1 + 2 * un);

    // 3. compute: two 32-j halfsteps
    const char* bufb = smem + (u & 1) * 32768;
#pragma unroll
    for (int h = 0; h < 2; ++h) {
      const uint32_t* pk = &PKs[u * 128 + h * 64 + g * 16];
      const u32x4 q0 = *(const u32x4*)(pk + 0);
      const u32x4 q1 = *(const u32x4*)(pk + 4);
      const u32x4 q2 = *(const u32x4*)(pk + 8);
      const u32x4 q3 = *(const u32x4*)(pk + 12);
      const uint32_t mb0 = (uint32_t)(cw0 >> (h * 32)) >> (g * 8);
      const uint32_t mb1 = (uint32_t)(cw1 >> (h * 32)) >> (g * 8);
      short8 af0 = build(T0, A0, C0, mb0, q0, q1, q2, q3, den0);
      short8 af1 = build(T1, A1, C1, mb1, q0, q1, q2, q3, den1);
      const short* bl = (const short*)bufb + (h * 4 + g) * 2048 +
                        (ns * 128 + m) * 8;
      __builtin_amdgcn_s_setprio(1);
#pragma unroll
      for (int nf = 0; nf < 8; ++nf) {
        short8 bf = *(const short8*)(bl + nf * 128);
        acc0[nf] = __builtin_amdgcn_mfma_f32_16x16x32_bf16(af0, bf, acc0[nf], 0, 0, 0);
        acc1[nf] = __builtin_amdgcn_mfma_f32_16x16x32_bf16(af1, bf, acc1[nf], 0, 0, 0);
      }
      __builtin_amdgcn_s_setprio(0);
    }
    cw0 = nw0; cw1 = nw1;
    // 4. single barrier per 64-j step
    __syncthreads();
  }

  // den reduce across the 4 k-groups
  den0 += __shfl_xor(den0, 16); den0 += __shfl_xor(den0, 32);
  den1 += __shfl_xor(den1, 16); den1 += __shfl_xor(den1, 32);
  if (ns == 0 && lane < 16) {
    pden[jc * NN + rb + m] = den0;
    pden[jc * NN + rb + 16 + m] = den1;
  }

  // each wave owns its disjoint 32x128 tile of pnum[jc]
  float* pn = pnum + (size_t)jc * NN * OUTD + (size_t)rb * OUTD + ns * 128;
#pragma unroll
  for (int r = 0; r < 4; ++r) {
    const int q = g * 4 + r;
#pragma unroll
    for (int nf = 0; nf < 8; ++nf) {
      pn[(size_t)q * OUTD + nf * 16 + m] = acc0[nf][r];
      pn[(size_t)(16 + q) * OUTD + nf * 16 + m] = acc1[nf][r];
    }
  }
}

extern "C" __global__ __launch_bounds__(256) void k_comb(
    const float* __restrict__ pnum, const float* __restrict__ pden,
    float* __restrict__ out) {
  const int idx = blockIdx.x * 256 + threadIdx.x;  // 524288 threads
  const int row = idx >> 6, c4 = (idx & 63) * 4;
  f32x4 s = (f32x4){0.f, 0.f, 0.f, 0.f};
  float d = 0.f;
#pragma unroll
  for (int jc = 0; jc < 8; ++jc) {
    f32x4 v = *(const f32x4*)(pnum + ((size_t)jc * NN + row) * OUTD + c4);
    s += v;
    d += pden[jc * NN + row];
  }
  const float inv = 1.f / d;
  *(f32x4*)(out + (size_t)row * OUTD + c4) = s * inv;
}

extern "C" void kernel_launch(void* const* d_in, const int* in_sizes, int n_in,
                              void* d_out, int out_size, void* d_ws, size_t ws_size,
                              hipStream_t stream) {
  const float* nodes = (const float*)d_in[0];
  const int*   mask  = (const int*)d_in[1];
  const float* W_w   = (const float*)d_in[2];
  const float* W_b   = (const float*)d_in[3];
  const float* a1w   = (const float*)d_in[4];
  const float* a1b   = (const float*)d_in[5];
  const float* a2w   = (const float*)d_in[6];
  const float* a2b   = (const float*)d_in[7];
  float* out = (float*)d_out;

  char* ws = (char*)d_ws;
  short*    WhL  = (short*)(ws);                                  // 4 MiB
  float*    s1   = (float*)(ws + (size_t)4  * 1024 * 1024);       // 32 KiB
  short*    W2   = (short*)(ws + (size_t)4  * 1024 * 1024 + 65536); // 256 KiB
  uint32_t* bmp  = (uint32_t*)(ws + (size_t)5  * 1024 * 1024);    // 8 MiB
  float*    sAC  = (float*)(ws + (size_t)13 * 1024 * 1024);       // 64 KiB
  uint32_t* sPK  = (uint32_t*)(ws + (size_t)14 * 1024 * 1024);    // 64 KiB
  float*    pnum = (float*)(ws + (size_t)16 * 1024 * 1024);       // 64 MiB
  float*    pden = (float*)(ws + (size_t)96 * 1024 * 1024);       // 256 KiB

  hipLaunchKernelGGL(k_mask, dim3(1024), dim3(256), 0, stream, mask, bmp);
  hipLaunchKernelGGL(k_convert_w, dim3(64), dim3(256), 0, stream, W_w, W2);
  hipLaunchKernelGGL(k_wh, dim3(256), dim3(128), 0, stream,
                     nodes, W2, W_b, a1w, a1b, a2w, a2b, WhL, s1, sAC, sPK);
  hipLaunchKernelGGL(k_attn, dim3(512), dim3(512), 0, stream,
                     bmp, WhL, s1, sAC, sPK, pnum, pden);
  hipLaunchKernelGGL(k_comb, dim3(2048), dim3(256), 0, stream,
                     pnum, pden, out);
}

// Round 12
// 229.531 us; speedup vs baseline: 1.7453x; 1.7453x over previous
//
#include <hip/hip_runtime.h>
#include <hip/hip_bf16.h>
#include <stdint.h>

// DenseGraphAttentionHead N=8192, IN=512, OUT=256, ~50% dense int32 mask.
//
// Pipeline:
//   k_mask      : int32 mask (268 MB, irreducible HBM stream) -> bitmask
//                 bm[row][wj] (8.4 MB) via __ballot. HBM-bound.
//   k_convert_w : W f32 -> bf16 chunked (16B chunk (kb,row) at kb*2048+row*8).
//   k_wh        : Wh = nodes@W^T + b (mfma) -> WhL chunked bf16 + s1 f32 +
//                 fused exp-factorization tables:
//                 P = mask * (s1+s2>0 ? e^{s1}e^{s2} : e^{.2s1}e^{.2s2})
//                 sAC=[e^{s1}|e^{.2s1}] f32; sPK[j]={f32 e^{s2},
//                 u32(e^{.2s2}bf16 hi | s2 bf16 lo)}.
//   k_attn      : BARRIER-FREE, ZERO-LDS. Grid 128rt x 8jc = 1024 blocks;
//                 block 256 thr = 4 waves = 2 rowgroups(32) x 2 colhalves
//                 (128); wave owns a disjoint 32x128 tile, acc = 64 AGPR
//                 (+~64 VGPR = 128 regs -> 4 waves/SIMD). All operands read
//                 directly (WhL chunked = one 16B load per B-frag, L2-slice-
//                 resident per XCD; PK/bm broadcast loads via L1). No
//                 __shared__, no __syncthreads -> compiler freely software-
//                 pipelines loads across build+MFMA (the per-step barrier
//                 convoy was the ~100us limiter in R6-R11).
//   k_comb      : out = sum_jc(pnum) / sum_jc(pden), 8 partials.
//
// MFMA conventions (verified R1-R11 on this problem):
//   A frag: lane&15 = m, k = (lane>>4)*8 + i ; B same per-lane k order
//   D: col = lane&15, row = (lane>>4)*4 + reg

#define NN 8192
#define IND 512
#define OUTD 256

typedef __attribute__((ext_vector_type(8))) short short8;
typedef __attribute__((ext_vector_type(4))) short short4v;
typedef __attribute__((ext_vector_type(4))) float f32x4;
typedef __attribute__((ext_vector_type(4))) unsigned int u32x4;

static __device__ __forceinline__ short f2bf(float f) {
  return __builtin_bit_cast(short, __float2bfloat16(f));
}

extern "C" __global__ __launch_bounds__(256) void k_convert_w(
    const float* __restrict__ W, short* __restrict__ W2) {
  const int t = blockIdx.x * 256 + threadIdx.x;  // 16384 threads
  const int row = t >> 6, kb = t & 63;
  const float* src = W + row * IND + kb * 8;
  f32x4 x0 = *(const f32x4*)src;
  f32x4 x1 = *(const f32x4*)(src + 4);
  short8 o;
  o[0] = f2bf(x0[0]); o[1] = f2bf(x0[1]); o[2] = f2bf(x0[2]); o[3] = f2bf(x0[3]);
  o[4] = f2bf(x1[0]); o[5] = f2bf(x1[1]); o[6] = f2bf(x1[2]); o[7] = f2bf(x1[3]);
  *(short8*)(W2 + (size_t)kb * 2048 + row * 8) = o;
}

extern "C" __global__ __launch_bounds__(128) void k_wh(
    const float* __restrict__ nodes, const short* __restrict__ W2,
    const float* __restrict__ Wb, const float* __restrict__ a1w,
    const float* __restrict__ a1b, const float* __restrict__ a2w,
    const float* __restrict__ a2b, short* __restrict__ WhL,
    float* __restrict__ s1, float* __restrict__ sAC,
    uint32_t* __restrict__ sPK) {
  const int tid = threadIdx.x;
  const int wv = tid >> 6, lane = tid & 63, g = lane >> 4, m = lane & 15;
  const int rowbase = blockIdx.x * 32 + wv * 16;

  f32x4 acc[16];
#pragma unroll
  for (int nf = 0; nf < 16; ++nf) acc[nf] = (f32x4){0.f, 0.f, 0.f, 0.f};

  const float* arow = nodes + (size_t)(rowbase + m) * IND;
  const short* bb = W2 + (size_t)g * 2048 + m * 8;
#pragma unroll 4
  for (int k0 = 0; k0 < IND; k0 += 32) {
    const float* ap = arow + k0 + g * 8;
    f32x4 x0 = *(const f32x4*)ap;
    f32x4 x1 = *(const f32x4*)(ap + 4);
    short8 af;
    af[0] = f2bf(x0[0]); af[1] = f2bf(x0[1]); af[2] = f2bf(x0[2]); af[3] = f2bf(x0[3]);
    af[4] = f2bf(x1[0]); af[5] = f2bf(x1[1]); af[6] = f2bf(x1[2]); af[7] = f2bf(x1[3]);
    const short* bk = bb + (size_t)(k0 >> 3) * 2048;
#pragma unroll
    for (int nf = 0; nf < 16; ++nf) {
      short8 bf = *(const short8*)(bk + nf * 128);
      acc[nf] = __builtin_amdgcn_mfma_f32_16x16x32_bf16(af, bf, acc[nf], 0, 0, 0);
    }
  }

  float p1[4] = {0.f, 0.f, 0.f, 0.f}, p2[4] = {0.f, 0.f, 0.f, 0.f};
#pragma unroll
  for (int nf = 0; nf < 16; ++nf) {
    const int n = nf * 16 + m;
    const float b = Wb[n], c1 = a1w[n], c2 = a2w[n];
#pragma unroll
    for (int r = 0; r < 4; ++r) {
      float v = acc[nf][r] + b;
      acc[nf][r] = v;
      p1[r] += c1 * v;
      p2[r] += c2 * v;
    }
  }
#pragma unroll
  for (int off = 1; off < 16; off <<= 1) {
#pragma unroll
    for (int r = 0; r < 4; ++r) {
      p1[r] += __shfl_xor(p1[r], off);
      p2[r] += __shfl_xor(p2[r], off);
    }
  }
  if (m == 0) {
    const float b1 = a1b[0], b2 = a2b[0];
#pragma unroll
    for (int r = 0; r < 4; ++r) {
      const int row = rowbase + g * 4 + r;
      const float v1 = p1[r] + b1, v2 = p2[r] + b2;
      s1[row] = v1;
      sAC[row] = __expf(v1);
      sAC[NN + row] = __expf(0.2f * v1);
      const float B = __expf(v2), D = __expf(0.2f * v2);
      sPK[2 * row] = __builtin_bit_cast(uint32_t, B);
      sPK[2 * row + 1] =
          ((uint32_t)(uint16_t)f2bf(D) << 16) | (uint16_t)f2bf(v2);
    }
  }

  const size_t cbase = ((size_t)(rowbase >> 3) + (g >> 1)) * 2048 + (g & 1) * 4;
#pragma unroll
  for (int nf = 0; nf < 16; ++nf) {
    short4v o;
#pragma unroll
    for (int r = 0; r < 4; ++r) o[r] = f2bf(acc[nf][r]);
    *(short4v*)(WhL + cbase + (size_t)(nf * 16 + m) * 8) = o;
  }
}

// int32 mask -> bitmask. bm[row*256 + wj] bit b = mask[row][wj*32+b] != 0.
extern "C" __global__ __launch_bounds__(256) void k_mask(
    const int* __restrict__ mask, uint32_t* __restrict__ bm) {
  const int tid = threadIdx.x;
  const int wv = tid >> 6, lane = tid & 63;
  const int gw = blockIdx.x * 4 + wv;           // 4096 waves
  const size_t base = (size_t)gw * 16384;       // 64 iters x 256 ints
#pragma unroll 4
  for (int it = 0; it < 64; ++it) {
    const size_t ib = base + (size_t)it * 256;
    unsigned long long b0 = __ballot(mask[ib + lane] != 0);
    unsigned long long b1 = __ballot(mask[ib + 64 + lane] != 0);
    unsigned long long b2 = __ballot(mask[ib + 128 + lane] != 0);
    unsigned long long b3 = __ballot(mask[ib + 192 + lane] != 0);
    if (lane < 8) {
      unsigned long long s01 = (lane & 2) ? b1 : b0;
      unsigned long long s23 = (lane & 2) ? b3 : b2;
      unsigned long long sel = (lane & 4) ? s23 : s01;
      bm[ib / 32 + lane] = (uint32_t)(sel >> ((lane & 1) * 32));
    }
  }
}

extern "C" __global__ __launch_bounds__(256, 4) void k_attn(
    const uint32_t* __restrict__ bm, const short* __restrict__ WhL,
    const float* __restrict__ s1, const float* __restrict__ sAC,
    const uint32_t* __restrict__ sPK,
    float* __restrict__ pnum, float* __restrict__ pden) {
  const int tid = threadIdx.x;
  const int w = tid >> 6, lane = tid & 63, g = lane >> 4, m = lane & 15;
  const int rt = blockIdx.x >> 3, jc = blockIdx.x & 7;
  const int rg = w & 1, ns = w >> 1;
  const int rb = rt * 64 + rg * 32;

  // per-lane row constants (rows rb+m and rb+16+m)
  const float T0 = -s1[rb + m],        T1 = -s1[rb + 16 + m];
  const float A0 = sAC[rb + m],        A1 = sAC[rb + 16 + m];
  const float C0 = sAC[NN + rb + m],   C1 = sAC[NN + rb + 16 + m];

  f32x4 acc0[8], acc1[8];
#pragma unroll
  for (int nf = 0; nf < 8; ++nf) {
    acc0[nf] = (f32x4){0.f, 0.f, 0.f, 0.f};
    acc1[nf] = (f32x4){0.f, 0.f, 0.f, 0.f};
  }
  float den0 = 0.f, den1 = 0.f;

  // bm: word u covers j [jc*1024 + u*32, +32)
  const uint32_t* bw0 = bm + (size_t)(rb + m) * 256 + jc * 32;
  const uint32_t* bw1 = bw0 + (size_t)16 * 256;
  // PK: 16 u32 per (step,g): {B f32, (Dbf16|s2bf16)} x 8 j
  const uint32_t* pk0 = sPK + 2 * (jc * 1024 + g * 8);
  // WhL chunked: B-frag for (step u, g, col n=ns*128+nf*16+m) is ONE 16B load
  // at shorts (jc*128 + u*4 + g)*2048 + n*8
  const short* bb = WhL + ((size_t)jc * 128 + g) * 2048 + (ns * 128 + m) * 8;

  auto build = [&](float T, float A, float C, uint32_t mbits,
                   const u32x4& q0, const u32x4& q1,
                   const u32x4& q2, const u32x4& q3, float& den) -> short8 {
    const uint32_t Bv[8] = {q0[0], q0[2], q1[0], q1[2],
                            q2[0], q2[2], q3[0], q3[2]};
    const uint32_t Dv[8] = {q0[1], q0[3], q1[1], q1[3],
                            q2[1], q2[3], q3[1], q3[3]};
    short8 af;
#pragma unroll
    for (int i = 0; i < 8; ++i) {
      const float s2v = __builtin_bit_cast(float, Dv[i] << 16);
      const bool pos = s2v > T;
      const float wv = __builtin_bit_cast(float, pos ? Bv[i] : (Dv[i] & 0xFFFF0000u));
      const float a = pos ? A : C;
      const float val = wv * a;
      const float pv = ((mbits >> i) & 1u) ? val : 0.f;
      den += pv;
      af[i] = f2bf(pv);
    }
    return af;
  };

#pragma unroll 2
  for (int u = 0; u < 32; ++u) {
    const uint32_t cw0 = bw0[u], cw1 = bw1[u];
    const uint32_t* pk = pk0 + u * 64;
    const u32x4 q0 = *(const u32x4*)(pk + 0);
    const u32x4 q1 = *(const u32x4*)(pk + 4);
    const u32x4 q2 = *(const u32x4*)(pk + 8);
    const u32x4 q3 = *(const u32x4*)(pk + 12);
    short8 af0 = build(T0, A0, C0, cw0 >> (g * 8), q0, q1, q2, q3, den0);
    short8 af1 = build(T1, A1, C1, cw1 >> (g * 8), q0, q1, q2, q3, den1);
    const short* bu = bb + (size_t)u * 8192;
#pragma unroll
    for (int nf = 0; nf < 8; ++nf) {
      short8 bf = *(const short8*)(bu + nf * 128);
      acc0[nf] = __builtin_amdgcn_mfma_f32_16x16x32_bf16(af0, bf, acc0[nf], 0, 0, 0);
      acc1[nf] = __builtin_amdgcn_mfma_f32_16x16x32_bf16(af1, bf, acc1[nf], 0, 0, 0);
    }
  }

  // den reduce across the 4 k-groups
  den0 += __shfl_xor(den0, 16); den0 += __shfl_xor(den0, 32);
  den1 += __shfl_xor(den1, 16); den1 += __shfl_xor(den1, 32);
  if (ns == 0 && lane < 16) {
    pden[jc * NN + rb + m] = den0;
    pden[jc * NN + rb + 16 + m] = den1;
  }

  // each wave owns its disjoint 32x128 tile of pnum[jc]
  float* pn = pnum + (size_t)jc * NN * OUTD + (size_t)rb * OUTD + ns * 128;
#pragma unroll
  for (int r = 0; r < 4; ++r) {
    const int q = g * 4 + r;
#pragma unroll
    for (int nf = 0; nf < 8; ++nf) {
      pn[(size_t)q * OUTD + nf * 16 + m] = acc0[nf][r];
      pn[(size_t)(16 + q) * OUTD + nf * 16 + m] = acc1[nf][r];
    }
  }
}

extern "C" __global__ __launch_bounds__(256) void k_comb(
    const float* __restrict__ pnum, const float* __restrict__ pden,
    float* __restrict__ out) {
  const int idx = blockIdx.x * 256 + threadIdx.x;  // 524288 threads
  const int row = idx >> 6, c4 = (idx & 63) * 4;
  f32x4 s = (f32x4){0.f, 0.f, 0.f, 0.f};
  float d = 0.f;
#pragma unroll
  for (int jc = 0; jc < 8; ++jc) {
    f32x4 v = *(const f32x4*)(pnum + ((size_t)jc * NN + row) * OUTD + c4);
    s += v;
    d += pden[jc * NN + row];
  }
  const float inv = 1.f / d;
  *(f32x4*)(out + (size_t)row * OUTD + c4) = s * inv;
}

extern "C" void kernel_launch(void* const* d_in, const int* in_sizes, int n_in,
                              void* d_out, int out_size, void* d_ws, size_t ws_size,
                              hipStream_t stream) {
  const float* nodes = (const float*)d_in[0];
  const int*   mask  = (const int*)d_in[1];
  const float* W_w   = (const float*)d_in[2];
  const float* W_b   = (const float*)d_in[3];
  const float* a1w   = (const float*)d_in[4];
  const float* a1b   = (const float*)d_in[5];
  const float* a2w   = (const float*)d_in[6];
  const float* a2b   = (const float*)d_in[7];
  float* out = (float*)d_out;

  char* ws = (char*)d_ws;
  short*    WhL  = (short*)(ws);                                  // 4 MiB
  float*    s1   = (float*)(ws + (size_t)4  * 1024 * 1024);       // 32 KiB
  short*    W2   = (short*)(ws + (size_t)4  * 1024 * 1024 + 65536); // 256 KiB
  uint32_t* bmp  = (uint32_t*)(ws + (size_t)5  * 1024 * 1024);    // 8 MiB
  float*    sAC  = (float*)(ws + (size_t)13 * 1024 * 1024);       // 64 KiB
  uint32_t* sPK  = (uint32_t*)(ws + (size_t)14 * 1024 * 1024);    // 64 KiB
  float*    pnum = (float*)(ws + (size_t)16 * 1024 * 1024);       // 64 MiB
  float*    pden = (float*)(ws + (size_t)96 * 1024 * 1024);       // 256 KiB

  hipLaunchKernelGGL(k_mask, dim3(1024), dim3(256), 0, stream, mask, bmp);
  hipLaunchKernelGGL(k_convert_w, dim3(64), dim3(256), 0, stream, W_w, W2);
  hipLaunchKernelGGL(k_wh, dim3(256), dim3(128), 0, stream,
                     nodes, W2, W_b, a1w, a1b, a2w, a2b, WhL, s1, sAC, sPK);
  hipLaunchKernelGGL(k_attn, dim3(1024), dim3(256), 0, stream,
                     bmp, WhL, s1, sAC, sPK, pnum, pden);
  hipLaunchKernelGGL(k_comb, dim3(2048), dim3(256), 0, stream,
                     pnum, pden, out);
}

// Round 13
// 198.614 us; speedup vs baseline: 2.0170x; 1.1557x over previous
//
#include <hip/hip_runtime.h>
#include <hip/hip_bf16.h>
#include <stdint.h>

// DenseGraphAttentionHead N=8192, IN=512, OUT=256, ~50% dense int32 mask.
//
// Pipeline (k_mask FUSED into k_attn — raw mask streamed through its idle
// VMEM pipe with 2-step-deep cooperative staging + counted vmcnt):
//   k_convert_w : W f32 -> bf16 chunked (16B chunk (kb,row) at kb*2048+row*8).
//   k_wh        : Wh = nodes@W^T + b (mfma) -> WhL chunked bf16 + s1 f32 +
//                 fused exp-factorization tables:
//                 P = mask * (s1+s2>0 ? e^{s1}e^{s2} : e^{.2s1}e^{.2s2})
//                 sAC=[e^{s1}|e^{.2s1}] f32; sPK[j]={f32 e^{s2},
//                 u32(e^{.2s2}bf16 hi | s2 bf16 lo)}.
//   k_attn      : masked-softmax @ Wh. R9 geometry: grid 64rt x 8jc = 512
//                 blocks (2/CU); 512 thr = 8 waves = 4 rowgroups(32) x
//                 2 colhalves(128); acc 64 AGPR; 16 waves/CU.
//                 Per step (32 j): issue mask window u+2 (2 nt dwordx4/thr),
//                 issue WhL slice u+1 (2 global_load_lds/thr), ONE counted
//                 s_waitcnt vmcnt(4) (drains prev step's loads, never 0),
//                 pack+ds_write mask bytes u+1, compute u (exp-free build
//                 from LDS byte-mask + PK, 16 MFMA), lgkmcnt(0)+raw barrier.
//                 Mask HBM stream (268 MB) hides in the stall bubbles.
//   k_comb      : out = sum_jc(pnum) / sum_jc(pden), 8 partials.
//
// MFMA conventions (verified R1-R12 on this problem):
//   A frag: lane&15 = m, k = (lane>>4)*8 + i ; B same per-lane k order
//   D: col = lane&15, row = (lane>>4)*4 + reg

#define NN 8192
#define IND 512
#define OUTD 256

typedef __attribute__((ext_vector_type(8))) short short8;
typedef __attribute__((ext_vector_type(4))) short short4v;
typedef __attribute__((ext_vector_type(4))) float f32x4;
typedef __attribute__((ext_vector_type(4))) int i32x4;
typedef __attribute__((ext_vector_type(4))) unsigned int u32x4;

#define AS_GLOBAL __attribute__((address_space(1)))
#define AS_LDS __attribute__((address_space(3)))

static __device__ __forceinline__ short f2bf(float f) {
  return __builtin_bit_cast(short, __float2bfloat16(f));
}

extern "C" __global__ __launch_bounds__(256) void k_convert_w(
    const float* __restrict__ W, short* __restrict__ W2) {
  const int t = blockIdx.x * 256 + threadIdx.x;  // 16384 threads
  const int row = t >> 6, kb = t & 63;
  const float* src = W + row * IND + kb * 8;
  f32x4 x0 = *(const f32x4*)src;
  f32x4 x1 = *(const f32x4*)(src + 4);
  short8 o;
  o[0] = f2bf(x0[0]); o[1] = f2bf(x0[1]); o[2] = f2bf(x0[2]); o[3] = f2bf(x0[3]);
  o[4] = f2bf(x1[0]); o[5] = f2bf(x1[1]); o[6] = f2bf(x1[2]); o[7] = f2bf(x1[3]);
  *(short8*)(W2 + (size_t)kb * 2048 + row * 8) = o;
}

extern "C" __global__ __launch_bounds__(128) void k_wh(
    const float* __restrict__ nodes, const short* __restrict__ W2,
    const float* __restrict__ Wb, const float* __restrict__ a1w,
    const float* __restrict__ a1b, const float* __restrict__ a2w,
    const float* __restrict__ a2b, short* __restrict__ WhL,
    float* __restrict__ s1, float* __restrict__ sAC,
    uint32_t* __restrict__ sPK) {
  const int tid = threadIdx.x;
  const int wv = tid >> 6, lane = tid & 63, g = lane >> 4, m = lane & 15;
  const int rowbase = blockIdx.x * 32 + wv * 16;

  f32x4 acc[16];
#pragma unroll
  for (int nf = 0; nf < 16; ++nf) acc[nf] = (f32x4){0.f, 0.f, 0.f, 0.f};

  const float* arow = nodes + (size_t)(rowbase + m) * IND;
  const short* bb = W2 + (size_t)g * 2048 + m * 8;
#pragma unroll 4
  for (int k0 = 0; k0 < IND; k0 += 32) {
    const float* ap = arow + k0 + g * 8;
    f32x4 x0 = *(const f32x4*)ap;
    f32x4 x1 = *(const f32x4*)(ap + 4);
    short8 af;
    af[0] = f2bf(x0[0]); af[1] = f2bf(x0[1]); af[2] = f2bf(x0[2]); af[3] = f2bf(x0[3]);
    af[4] = f2bf(x1[0]); af[5] = f2bf(x1[1]); af[6] = f2bf(x1[2]); af[7] = f2bf(x1[3]);
    const short* bk = bb + (size_t)(k0 >> 3) * 2048;
#pragma unroll
    for (int nf = 0; nf < 16; ++nf) {
      short8 bf = *(const short8*)(bk + nf * 128);
      acc[nf] = __builtin_amdgcn_mfma_f32_16x16x32_bf16(af, bf, acc[nf], 0, 0, 0);
    }
  }

  float p1[4] = {0.f, 0.f, 0.f, 0.f}, p2[4] = {0.f, 0.f, 0.f, 0.f};
#pragma unroll
  for (int nf = 0; nf < 16; ++nf) {
    const int n = nf * 16 + m;
    const float b = Wb[n], c1 = a1w[n], c2 = a2w[n];
#pragma unroll
    for (int r = 0; r < 4; ++r) {
      float v = acc[nf][r] + b;
      acc[nf][r] = v;
      p1[r] += c1 * v;
      p2[r] += c2 * v;
    }
  }
#pragma unroll
  for (int off = 1; off < 16; off <<= 1) {
#pragma unroll
    for (int r = 0; r < 4; ++r) {
      p1[r] += __shfl_xor(p1[r], off);
      p2[r] += __shfl_xor(p2[r], off);
    }
  }
  if (m == 0) {
    const float b1 = a1b[0], b2 = a2b[0];
#pragma unroll
    for (int r = 0; r < 4; ++r) {
      const int row = rowbase + g * 4 + r;
      const float v1 = p1[r] + b1, v2 = p2[r] + b2;
      s1[row] = v1;
      sAC[row] = __expf(v1);
      sAC[NN + row] = __expf(0.2f * v1);
      const float B = __expf(v2), D = __expf(0.2f * v2);
      sPK[2 * row] = __builtin_bit_cast(uint32_t, B);
      sPK[2 * row + 1] =
          ((uint32_t)(uint16_t)f2bf(D) << 16) | (uint16_t)f2bf(v2);
    }
  }

  const size_t cbase = ((size_t)(rowbase >> 3) + (g >> 1)) * 2048 + (g & 1) * 4;
#pragma unroll
  for (int nf = 0; nf < 16; ++nf) {
    short4v o;
#pragma unroll
    for (int r = 0; r < 4; ++r) o[r] = f2bf(acc[nf][r]);
    *(short4v*)(WhL + cbase + (size_t)(nf * 16 + m) * 8) = o;
  }
}

extern "C" __global__ __launch_bounds__(512, 4) void k_attn(
    const int* __restrict__ mask, const short* __restrict__ WhL,
    const float* __restrict__ s1, const float* __restrict__ sAC,
    const uint32_t* __restrict__ sPK,
    float* __restrict__ pnum, float* __restrict__ pden) {
  // LDS: [0,32768) Bs dbuf 2x16KB; [32768,40960) PK 8KB;
  //      [40960,51200) mask byte dbuf 2 x [128 rows][40B]
  __shared__ char smem[51200];
  uint32_t* PKs = (uint32_t*)(smem + 32768);
  char* Ms = smem + 40960;

  const int tid = threadIdx.x;
  const int w = tid >> 6, lane = tid & 63, g = lane >> 4, m = lane & 15;
  const int rt = blockIdx.x >> 3, jc = blockIdx.x & 7;
  const int rg = w & 3, ns = w >> 2;
  const int rb = rt * 128 + rg * 32;

  const float T0 = -s1[rb + m],        T1 = -s1[rb + 16 + m];
  const float A0 = sAC[rb + m],        A1 = sAC[rb + 16 + m];
  const float C0 = sAC[NN + rb + m],   C1 = sAC[NN + rb + 16 + m];

  f32x4 acc0[8], acc1[8];
#pragma unroll
  for (int nf = 0; nf < 8; ++nf) {
    acc0[nf] = (f32x4){0.f, 0.f, 0.f, 0.f};
    acc1[nf] = (f32x4){0.f, 0.f, 0.f, 0.f};
  }
  float den0 = 0.f, den1 = 0.f;

  // mask loader mapping: thread covers (row rloc, ints [jq*8, jq*8+8)) of the
  // block's current 32-j window
  const int rloc = tid >> 2, jq = tid & 3;
  const int* msrc = mask + (size_t)(rt * 128 + rloc) * NN + jc * 1024 + jq * 8;
  const int mwr = rloc * 40 + jq * 8;  // LDS byte offset within buffer
  // build-side mask rows
  const int mrow0 = (rg * 32 + m) * 40 + g * 8;
  const int mrow1 = (rg * 32 + 16 + m) * 40 + g * 8;
  const short* gS = WhL + (size_t)jc * 262144;

  auto pack8 = [](const i32x4& a, const i32x4& b) -> uint64_t {
    uint64_t p = 0;
    p |= (a[0] != 0) ? 1ull : 0;
    p |= (a[1] != 0) ? (1ull << 8) : 0;
    p |= (a[2] != 0) ? (1ull << 16) : 0;
    p |= (a[3] != 0) ? (1ull << 24) : 0;
    p |= (b[0] != 0) ? (1ull << 32) : 0;
    p |= (b[1] != 0) ? (1ull << 40) : 0;
    p |= (b[2] != 0) ? (1ull << 48) : 0;
    p |= (b[3] != 0) ? (1ull << 56) : 0;
    return p;
  };

  auto build = [&](float T, float A, float C, uint64_t pb,
                   const u32x4& q0, const u32x4& q1,
                   const u32x4& q2, const u32x4& q3, float& den) -> short8 {
    const uint32_t Bv[8] = {q0[0], q0[2], q1[0], q1[2],
                            q2[0], q2[2], q3[0], q3[2]};
    const uint32_t Dv[8] = {q0[1], q0[3], q1[1], q1[3],
                            q2[1], q2[3], q3[1], q3[3]};
    short8 af;
#pragma unroll
    for (int i = 0; i < 8; ++i) {
      const float s2v = __builtin_bit_cast(float, Dv[i] << 16);
      const bool pos = s2v > T;
      const float wv = __builtin_bit_cast(float, pos ? Bv[i] : (Dv[i] & 0xFFFF0000u));
      const float a = pos ? A : C;
      const float val = wv * a;
      const float pv = ((pb >> (8 * i)) & 1) ? val : 0.f;
      den += pv;
      af[i] = f2bf(pv);
    }
    return af;
  };

  // ---- prologue ----
  // window 0 -> regset A
  i32x4 mA0 = __builtin_nontemporal_load((const i32x4*)msrc);
  i32x4 mA1 = __builtin_nontemporal_load((const i32x4*)(msrc + 4));
  // PK (8 KB, one gload/thread)
  __builtin_amdgcn_global_load_lds(
      (const AS_GLOBAL void*)((const char*)sPK + (size_t)jc * 8192 + tid * 16),
      (AS_LDS void*)(smem + 32768 + tid * 16), 16, 0, 0);
  // WhL slice 0 -> Bs[0] (2 gloads/thread)
  __builtin_amdgcn_global_load_lds((const AS_GLOBAL void*)(gS + tid * 8),
                                   (AS_LDS void*)(smem + tid * 16), 16, 0, 0);
  __builtin_amdgcn_global_load_lds((const AS_GLOBAL void*)(gS + 4096 + tid * 8),
                                   (AS_LDS void*)(smem + 8192 + tid * 16), 16, 0, 0);
  // pack+write window 0 into Ms[0] (compiler inserts the vmcnt for mA)
  *(uint64_t*)(Ms + mwr) = pack8(mA0, mA1);
  // window 1 -> regset B
  i32x4 mB0 = __builtin_nontemporal_load((const i32x4*)(msrc + 32));
  i32x4 mB1 = __builtin_nontemporal_load((const i32x4*)(msrc + 36));
  // drain PK + slice0 (leaves window-1's 2 loads in flight)
  asm volatile("s_waitcnt vmcnt(2)" ::: "memory");
  __builtin_amdgcn_sched_barrier(0);
  asm volatile("s_waitcnt lgkmcnt(0)" ::: "memory");
  __builtin_amdgcn_s_barrier();

  // ---- main loop: 32 steps, 2-unrolled for static regset naming ----
  auto body = [&](int u, i32x4& is0, i32x4& is1, i32x4& cs0, i32x4& cs1) {
    // 1. issue mask window u+2 into the issue-regset (clamped at tail)
    const int wn = (u + 2 < 32) ? u + 2 : 31;
    is0 = __builtin_nontemporal_load((const i32x4*)(msrc + wn * 32));
    is1 = __builtin_nontemporal_load((const i32x4*)(msrc + wn * 32 + 4));
    // 2. issue WhL slice u+1 into Bs[(u+1)&1] (clamped; dead at tail)
    const int us = (u + 1 < 32) ? u + 1 : 31;
    {
      const short* gsl = gS + us * 8192 + tid * 8;
      char* dst = smem + ((u + 1) & 1) * 16384 + tid * 16;
      __builtin_amdgcn_global_load_lds((const AS_GLOBAL void*)gsl,
                                       (AS_LDS void*)dst, 16, 0, 0);
      __builtin_amdgcn_global_load_lds((const AS_GLOBAL void*)(gsl + 4096),
                                       (AS_LDS void*)(dst + 8192), 16, 0, 0);
    }
    // 3. counted wait: drains prev step's {mask(u+1) x2, gl(u) x2}; 4 newer
    //    loads stay in flight. Never vmcnt(0) in the loop.
    asm volatile("s_waitcnt vmcnt(4)" ::: "memory");
    __builtin_amdgcn_sched_barrier(0);
    // 4. pack + write mask window u+1 from the consume-regset
    if (u < 31) *(uint64_t*)(Ms + ((u + 1) & 1) * 5120 + mwr) = pack8(cs0, cs1);
    // 5. compute step u
    const uint64_t pb0 = *(const uint64_t*)(Ms + (u & 1) * 5120 + mrow0);
    const uint64_t pb1 = *(const uint64_t*)(Ms + (u & 1) * 5120 + mrow1);
    const uint32_t* pk = &PKs[u * 64 + g * 16];
    const u32x4 q0 = *(const u32x4*)(pk + 0);
    const u32x4 q1 = *(const u32x4*)(pk + 4);
    const u32x4 q2 = *(const u32x4*)(pk + 8);
    const u32x4 q3 = *(const u32x4*)(pk + 12);
    short8 af0 = build(T0, A0, C0, pb0, q0, q1, q2, q3, den0);
    short8 af1 = build(T1, A1, C1, pb1, q0, q1, q2, q3, den1);
    const short* bl = (const short*)(smem + (u & 1) * 16384) +
                      g * 2048 + (ns * 128 + m) * 8;
#pragma unroll
    for (int nf = 0; nf < 8; ++nf) {
      short8 bf = *(const short8*)(bl + nf * 128);
      acc0[nf] = __builtin_amdgcn_mfma_f32_16x16x32_bf16(af0, bf, acc0[nf], 0, 0, 0);
      acc1[nf] = __builtin_amdgcn_mfma_f32_16x16x32_bf16(af1, bf, acc1[nf], 0, 0, 0);
    }
    // 6. LDS visible, then raw barrier (no vmcnt drain!)
    asm volatile("s_waitcnt lgkmcnt(0)" ::: "memory");
    __builtin_amdgcn_s_barrier();
  };

  for (int uu = 0; uu < 32; uu += 2) {
    body(uu, mA0, mA1, mB0, mB1);      // issue into A, consume B (w uu+1)
    body(uu + 1, mB0, mB1, mA0, mA1);  // issue into B, consume A (w uu+2)
  }

  // den reduce across the 4 k-groups
  den0 += __shfl_xor(den0, 16); den0 += __shfl_xor(den0, 32);
  den1 += __shfl_xor(den1, 16); den1 += __shfl_xor(den1, 32);
  if (ns == 0 && lane < 16) {
    pden[jc * NN + rb + m] = den0;
    pden[jc * NN + rb + 16 + m] = den1;
  }

  // each wave owns its disjoint 32x128 tile of pnum[jc]
  float* pn = pnum + (size_t)jc * NN * OUTD + (size_t)rb * OUTD + ns * 128;
#pragma unroll
  for (int r = 0; r < 4; ++r) {
    const int q = g * 4 + r;
#pragma unroll
    for (int nf = 0; nf < 8; ++nf) {
      pn[(size_t)q * OUTD + nf * 16 + m] = acc0[nf][r];
      pn[(size_t)(16 + q) * OUTD + nf * 16 + m] = acc1[nf][r];
    }
  }
}

extern "C" __global__ __launch_bounds__(256) void k_comb(
    const float* __restrict__ pnum, const float* __restrict__ pden,
    float* __restrict__ out) {
  const int idx = blockIdx.x * 256 + threadIdx.x;  // 524288 threads
  const int row = idx >> 6, c4 = (idx & 63) * 4;
  f32x4 s = (f32x4){0.f, 0.f, 0.f, 0.f};
  float d = 0.f;
#pragma unroll
  for (int jc = 0; jc < 8; ++jc) {
    f32x4 v = *(const f32x4*)(pnum + ((size_t)jc * NN + row) * OUTD + c4);
    s += v;
    d += pden[jc * NN + row];
  }
  const float inv = 1.f / d;
  *(f32x4*)(out + (size_t)row * OUTD + c4) = s * inv;
}

extern "C" void kernel_launch(void* const* d_in, const int* in_sizes, int n_in,
                              void* d_out, int out_size, void* d_ws, size_t ws_size,
                              hipStream_t stream) {
  const float* nodes = (const float*)d_in[0];
  const int*   mask  = (const int*)d_in[1];
  const float* W_w   = (const float*)d_in[2];
  const float* W_b   = (const float*)d_in[3];
  const float* a1w   = (const float*)d_in[4];
  const float* a1b   = (const float*)d_in[5];
  const float* a2w   = (const float*)d_in[6];
  const float* a2b   = (const float*)d_in[7];
  float* out = (float*)d_out;

  char* ws = (char*)d_ws;
  short*    WhL  = (short*)(ws);                                    // 4 MiB
  float*    s1   = (float*)(ws + (size_t)4  * 1024 * 1024);         // 32 KiB
  short*    W2   = (short*)(ws + (size_t)4  * 1024 * 1024 + 65536); // 256 KiB
  float*    sAC  = (float*)(ws + (size_t)13 * 1024 * 1024);         // 64 KiB
  uint32_t* sPK  = (uint32_t*)(ws + (size_t)14 * 1024 * 1024);      // 64 KiB
  float*    pnum = (float*)(ws + (size_t)16 * 1024 * 1024);         // 64 MiB
  float*    pden = (float*)(ws + (size_t)96 * 1024 * 1024);         // 256 KiB

  hipLaunchKernelGGL(k_convert_w, dim3(64), dim3(256), 0, stream, W_w, W2);
  hipLaunchKernelGGL(k_wh, dim3(256), dim3(128), 0, stream,
                     nodes, W2, W_b, a1w, a1b, a2w, a2b, WhL, s1, sAC, sPK);
  hipLaunchKernelGGL(k_attn, dim3(512), dim3(512), 0, stream,
                     mask, WhL, s1, sAC, sPK, pnum, pden);
  hipLaunchKernelGGL(k_comb, dim3(2048), dim3(256), 0, stream,
                     pnum, pden, out);
}